// Round 8
// baseline (837.565 us; speedup 1.0000x reference)
//
#include <hip/hip_runtime.h>
#include <hip/hip_bf16.h>
#include <math.h>

// ---------------------------------------------------------------------------
// InfNet: 2-layer GCN + Weibull epilogue.
// GEMMs: bf16x3 split as ONE pass: [Ah|Al|Ah] * [Bh;Bh;Bl] via K-wrap remap,
// with dinv[row] scaling fused into the GEMM epilogue (T1s=(x@W0)*dinv,
// T2s=(H1@W1)*dinv; T2k prescaled by dinv).
// Aggregations fp32, wave-per-node (verified at its delivery-BW roofline:
// 1.69GB @ ~7.3TB/s across 4 structural variants, r1/r2/r4/r7).
// agg1 is split into TWO node-range dispatches (identical total work) so the
// top-5 profile window (threshold = slowest dispatch) drops from 230us to
// ~118us, exposing the never-yet-profiled second tier (agg2/gemm1/conv_x).
// ---------------------------------------------------------------------------

typedef unsigned short ushort_t;
typedef __attribute__((ext_vector_type(8))) short bf16x8;
typedef __attribute__((ext_vector_type(4))) float f32x4;

__device__ __forceinline__ ushort_t f2bf(float f) {
    union { float f; unsigned u; } x; x.f = f;
    unsigned r = x.u + 0x7FFF + ((x.u >> 16) & 1);   // RNE
    return (ushort_t)(r >> 16);
}
__device__ __forceinline__ float bf2f(ushort_t s) {
    union { unsigned u; float f; } x; x.u = ((unsigned)s) << 16; return x.f;
}

__device__ __forceinline__ void async_copy16(const void* gsrc, void* ldst) {
    __builtin_amdgcn_global_load_lds(
        (const __attribute__((address_space(1))) unsigned int*)gsrc,
        (__attribute__((address_space(3))) unsigned int*)ldst,
        16, 0, 0);
}

// ---------------- graph preprocessing (plain CSR) ----------------

__global__ __launch_bounds__(256) void count_kernel(const int* __restrict__ dst,
                                                    int* __restrict__ cnt, int E)
{
    int e = blockIdx.x * blockDim.x + threadIdx.x;
    if (e < E) atomicAdd(&cnt[dst[e]], 1);
}

__global__ __launch_bounds__(1024) void scan_local(const int* __restrict__ cnt,
                                                   int* __restrict__ rowptr,
                                                   float* __restrict__ dinv,
                                                   int* __restrict__ blksum, int N)
{
    __shared__ int wsum[16];
    int tid = threadIdx.x, lane = tid & 63, wid = tid >> 6;
    int i = blockIdx.x * 1024 + tid;
    int v = (i < N) ? cnt[i] : 0;
    if (i < N) dinv[i] = rsqrtf((float)(v + 1));
    int s = v;
#pragma unroll
    for (int off = 1; off < 64; off <<= 1) {
        int t = __shfl_up(s, off, 64);
        if (lane >= off) s += t;
    }
    if (lane == 63) wsum[wid] = s;
    __syncthreads();
    if (tid < 16) {
        int w = wsum[tid];
#pragma unroll
        for (int off = 1; off < 16; off <<= 1) {
            int t = __shfl_up(w, off, 64);
            if (tid >= off) w += t;
        }
        wsum[tid] = w;
    }
    __syncthreads();
    int excl = s - v + (wid ? wsum[wid - 1] : 0);
    if (i < N) rowptr[i] = excl;
    if (tid == 0) blksum[blockIdx.x] = wsum[15];
}

__global__ __launch_bounds__(64) void scan_blk(const int* __restrict__ blksum,
                                               int* __restrict__ blkoff,
                                               int nblk, int* __restrict__ rowptr, int N)
{
    int tid = threadIdx.x;
    int v = (tid < nblk) ? blksum[tid] : 0;
    int s = v;
#pragma unroll
    for (int off = 1; off < 64; off <<= 1) {
        int t = __shfl_up(s, off, 64);
        if (tid >= off) s += t;
    }
    if (tid < nblk) blkoff[tid] = s - v;
    if (tid == nblk - 1) rowptr[N] = s;
}

__global__ __launch_bounds__(256) void scan_add(int* __restrict__ rowptr,
                                                int* __restrict__ cursor,
                                                const int* __restrict__ blkoff, int N)
{
    int i = blockIdx.x * blockDim.x + threadIdx.x;
    if (i < N) {
        int r = rowptr[i] + blkoff[i >> 10];
        rowptr[i] = r;
        cursor[i] = r;
    }
}

__global__ __launch_bounds__(256) void scatter_kernel(const int* __restrict__ src,
                                                      const int* __restrict__ dst,
                                                      int* __restrict__ cursor,
                                                      int* __restrict__ col, int E)
{
    int e = blockIdx.x * blockDim.x + threadIdx.x;
    if (e < E) {
        int d = dst[e];
        int pos = atomicAdd(&cursor[d], 1);
        col[pos] = src[e];
    }
}

// ---------------- operand conversion (bf16 hi/lo split) ----------------

__global__ __launch_bounds__(256) void conv_x(const float* __restrict__ x,
                                              ushort_t* __restrict__ Abig,
                                              int M, int M_pad)
{
    int id = blockIdx.x * blockDim.x + threadIdx.x;
    int r = id >> 7, q = id & 127;
    if (r >= M_pad) return;
    float4 v = make_float4(0.f, 0.f, 0.f, 0.f);
    if (r < M) v = *reinterpret_cast<const float4*>(&x[(size_t)r * 512 + q * 4]);
    ushort4 h, l;
    h.x = f2bf(v.x); l.x = f2bf(v.x - bf2f(h.x));
    h.y = f2bf(v.y); l.y = f2bf(v.y - bf2f(h.y));
    h.z = f2bf(v.z); l.z = f2bf(v.z - bf2f(h.z));
    h.w = f2bf(v.w); l.w = f2bf(v.w - bf2f(h.w));
    ushort_t* rowp = Abig + (size_t)r * 1024;
    *reinterpret_cast<ushort4*>(rowp + q * 4)       = h;
    *reinterpret_cast<ushort4*>(rowp + 512 + q * 4) = l;
}

// W0bigT (256 x 1536), row n: [hi(512) | hi(512) | lo(512)] of W0[:,n].
__global__ __launch_bounds__(256) void conv_w0(const float* __restrict__ W0,
                                               ushort_t* __restrict__ BT)
{
    int id = blockIdx.x * blockDim.x + threadIdx.x;
    int k = id & 511, n = id >> 9;
    if (n >= 256) return;
    float v = W0[(size_t)k * 256 + n];
    ushort_t h = f2bf(v);
    ushort_t l = f2bf(v - bf2f(h));
    ushort_t* rowp = BT + (size_t)n * 1536;
    rowp[k] = h; rowp[512 + k] = h; rowp[1024 + k] = l;
}

// W1bigT (128 x 768), row n: [hi(256) | hi(256) | lo(256)]; plus W1col fp32.
__global__ __launch_bounds__(256) void conv_w1(const float* __restrict__ W1,
                                               ushort_t* __restrict__ BT,
                                               float* __restrict__ W1col)
{
    int id = blockIdx.x * blockDim.x + threadIdx.x;
    int k = id & 255, n = id >> 8;
    if (n >= 128) return;
    float v = W1[(size_t)k * 129 + n];
    ushort_t h = f2bf(v);
    ushort_t l = f2bf(v - bf2f(h));
    ushort_t* rowp = BT + (size_t)n * 768;
    rowp[k] = h; rowp[256 + k] = h; rowp[512 + k] = l;
    if (n == 0) W1col[k] = W1[(size_t)k * 129 + 128];
}

// ---------------- MFMA GEMM: C = (A * BT^T) * rowscale[r] ----------------
// K iterates [0, K); A's k-index wraps at kwrap (so Ah reused for the Bl band).
// 128x128 tile, BK=32, 256 thr = 4 waves (2x2 of 64x64), 16x16x32 MFMA.
__global__ __launch_bounds__(256) void gemm_bf16(const ushort_t* __restrict__ A, int lda,
                                                 const ushort_t* __restrict__ BT, int ldbt,
                                                 float* __restrict__ C, int ldc,
                                                 int M, int K, int kwrap,
                                                 const float* __restrict__ rowscale)
{
    __shared__ short As[128 * 32];
    __shared__ short Bs[128 * 32];

    int tid  = threadIdx.x;
    int w    = tid >> 6;
    int lane = tid & 63;
    int lm   = lane & 15;
    int lq   = lane >> 4;
    int bm   = blockIdx.x * 128;
    int bn   = blockIdx.y * 128;
    int wr   = (w >> 1) * 64;
    int wc   = (w & 1) * 64;

    f32x4 acc[4][4];
#pragma unroll
    for (int i = 0; i < 4; ++i)
#pragma unroll
        for (int j = 0; j < 4; ++j) acc[i][j] = (f32x4)(0.f);

    int srow = (lane >> 2);
    int scol = (lane & 3) * 16;

    for (int k0 = 0; k0 < K; k0 += 32) {
        int ka = (k0 < kwrap) ? k0 : (k0 - kwrap);   // A k-wrap (tiles never straddle)
#pragma unroll
        for (int q = 0; q < 2; ++q) {
            int r = w * 32 + q * 16 + srow;
            const char* ga = (const char*)A + ((size_t)(bm + r) * lda + ka) * 2 + scol;
            async_copy16(ga, (char*)As + (size_t)(w * 32 + q * 16) * 64);
        }
#pragma unroll
        for (int q = 0; q < 2; ++q) {
            int r = w * 32 + q * 16 + srow;
            const char* gb = (const char*)BT + ((size_t)(bn + r) * ldbt + k0) * 2 + scol;
            async_copy16(gb, (char*)Bs + (size_t)(w * 32 + q * 16) * 64);
        }
        __syncthreads();

        bf16x8 afr[4], bfr[4];
#pragma unroll
        for (int mi = 0; mi < 4; ++mi)
            afr[mi] = *reinterpret_cast<const bf16x8*>(&As[(wr + mi * 16 + lm) * 32 + lq * 8]);
#pragma unroll
        for (int ni = 0; ni < 4; ++ni)
            bfr[ni] = *reinterpret_cast<const bf16x8*>(&Bs[(wc + ni * 16 + lm) * 32 + lq * 8]);
#pragma unroll
        for (int mi = 0; mi < 4; ++mi)
#pragma unroll
            for (int ni = 0; ni < 4; ++ni)
                acc[mi][ni] = __builtin_amdgcn_mfma_f32_16x16x32_bf16(
                    afr[mi], bfr[ni], acc[mi][ni], 0, 0, 0);
        __syncthreads();
    }

#pragma unroll
    for (int mi = 0; mi < 4; ++mi) {
        int rbase = bm + wr + mi * 16 + lq * 4;
        float rs[4];
#pragma unroll
        for (int e = 0; e < 4; ++e)                 // ni-invariant: hoisted
            rs[e] = (rbase + e < M) ? rowscale[rbase + e] : 0.f;
#pragma unroll
        for (int ni = 0; ni < 4; ++ni) {
            int cc = bn + wc + ni * 16 + lm;
#pragma unroll
            for (int e = 0; e < 4; ++e) {
                int r = rbase + e;
                if (r < M) C[(size_t)r * ldc + cc] = acc[mi][ni][e] * rs[e];
            }
        }
    }
}

// ---------------- fused pieces ----------------

__device__ __forceinline__ float softplus_f(float x)
{
    return fmaxf(x, 0.f) + log1pf(expf(-fabsf(x)));
}

__device__ __forceinline__ void add4(float4& a, const float4& v)
{
    a.x += v.x; a.y += v.y; a.z += v.z; a.w += v.w;
}

__device__ __forceinline__ void add2(float2& a, const float2& v)
{
    a.x += v.x; a.y += v.y;
}

// layer-1 aggregation + softplus -> H1big bf16 [hi(256) | lo(256)] per node;
// fused kappa column dot (T2ks = dinv * (H1 . W1col)).
// Wave-per-node; rows prescaled by dinv[src]; node range [node0, node1)
// (two dispatches, identical total work -> profiling visibility).
__global__ __launch_bounds__(256) void agg1_kernel(const float* __restrict__ T1s,
                                                   const float* __restrict__ dinv,
                                                   const int* __restrict__ rowptr,
                                                   const int* __restrict__ col,
                                                   const float* __restrict__ W1col,
                                                   ushort_t* __restrict__ H1big,
                                                   float* __restrict__ T2k,
                                                   int node0, int node1)
{
    int wslot = __builtin_amdgcn_readfirstlane(threadIdx.x >> 6);  // wave-uniform
    int node  = node0 + blockIdx.x * 4 + wslot;
    if (node >= node1) return;
    int lane = threadIdx.x & 63;
    float di = dinv[node];
    int beg = rowptr[node], end = rowptr[node + 1];

    float4 a0 = make_float4(0.f, 0.f, 0.f, 0.f);
    float4 a1 = a0, a2 = a0, a3 = a0;

    const float* Trow = T1s + (size_t)lane * 4;   // per-lane column offset

    int e = beg;
    for (; e + 4 <= end; e += 4) {
        int s0 = col[e], s1 = col[e + 1], s2 = col[e + 2], s3 = col[e + 3];
        float4 v0 = *reinterpret_cast<const float4*>(Trow + (size_t)s0 * 256);
        float4 v1 = *reinterpret_cast<const float4*>(Trow + (size_t)s1 * 256);
        float4 v2 = *reinterpret_cast<const float4*>(Trow + (size_t)s2 * 256);
        float4 v3 = *reinterpret_cast<const float4*>(Trow + (size_t)s3 * 256);
        add4(a0, v0); add4(a1, v1); add4(a2, v2); add4(a3, v3);
    }
    for (; e < end; ++e) {
        int s = col[e];
        float4 v = *reinterpret_cast<const float4*>(Trow + (size_t)s * 256);
        add4(a0, v);
    }

    float4 self = *reinterpret_cast<const float4*>(Trow + (size_t)node * 256);
    float4 o;
    o.x = softplus_f((a0.x + a1.x + a2.x + a3.x + self.x) * di);
    o.y = softplus_f((a0.y + a1.y + a2.y + a3.y + self.y) * di);
    o.z = softplus_f((a0.z + a1.z + a2.z + a3.z + self.z) * di);
    o.w = softplus_f((a0.w + a1.w + a2.w + a3.w + self.w) * di);

    ushort4 h, l;
    h.x = f2bf(o.x); l.x = f2bf(o.x - bf2f(h.x));
    h.y = f2bf(o.y); l.y = f2bf(o.y - bf2f(h.y));
    h.z = f2bf(o.z); l.z = f2bf(o.z - bf2f(h.z));
    h.w = f2bf(o.w); l.w = f2bf(o.w - bf2f(h.w));
    ushort_t* rowp = H1big + (size_t)node * 512;
    *reinterpret_cast<ushort4*>(rowp + lane * 4)       = h;
    *reinterpret_cast<ushort4*>(rowp + 256 + lane * 4) = l;

    // fused kappa column, prescaled: T2ks[node] = dinv[node] * (H1[node,:].W1col)
    float4 wv = *reinterpret_cast<const float4*>(&W1col[lane * 4]);
    float tk = o.x * wv.x + o.y * wv.y + o.z * wv.z + o.w * wv.w;
#pragma unroll
    for (int off = 32; off > 0; off >>= 1)
        tk += __shfl_down(tk, off, 64);
    if (lane == 0) T2k[node] = tk * di;
}

// layer-2 aggregation + softplus + Weibull epilogue. Wave-per-node; rows and
// T2k prescaled by dinv[src], so per edge: gather + add, T2k broadcast + add.
__global__ __launch_bounds__(256) void agg2_kernel(const float* __restrict__ T2s,
                                                   const float* __restrict__ T2k,
                                                   const float* __restrict__ dinv,
                                                   const int* __restrict__ rowptr,
                                                   const int* __restrict__ col,
                                                   float* __restrict__ z_out,
                                                   float* __restrict__ lbd_out,
                                                   float* __restrict__ kap_out, int N)
{
    int wslot = __builtin_amdgcn_readfirstlane(threadIdx.x >> 6);  // wave-uniform
    int node  = blockIdx.x * 4 + wslot;
    if (node >= N) return;
    int lane = threadIdx.x & 63;
    float di = dinv[node];
    int beg = rowptr[node], end = rowptr[node + 1];

    float2 a0 = make_float2(0.f, 0.f);
    float2 a1 = a0, a2 = a0, a3 = a0;
    float k0 = 0.f, k1 = 0.f, k2 = 0.f, k3 = 0.f;

    const float* Trow = T2s + (size_t)lane * 2;

    int e = beg;
    for (; e + 4 <= end; e += 4) {
        int s0 = col[e], s1 = col[e + 1], s2 = col[e + 2], s3 = col[e + 3];
        k0 += T2k[s0]; k1 += T2k[s1]; k2 += T2k[s2]; k3 += T2k[s3];
        float2 v0 = *reinterpret_cast<const float2*>(Trow + (size_t)s0 * 128);
        float2 v1 = *reinterpret_cast<const float2*>(Trow + (size_t)s1 * 128);
        float2 v2 = *reinterpret_cast<const float2*>(Trow + (size_t)s2 * 128);
        float2 v3 = *reinterpret_cast<const float2*>(Trow + (size_t)s3 * 128);
        add2(a0, v0); add2(a1, v1); add2(a2, v2); add2(a3, v3);
    }
    for (; e < end; ++e) {
        int s = col[e];
        k0 += T2k[s];
        float2 v = *reinterpret_cast<const float2*>(Trow + (size_t)s * 128);
        add2(a0, v);
    }

    float2 self = *reinterpret_cast<const float2*>(Trow + (size_t)node * 128);
    float2 sp;
    sp.x = softplus_f((a0.x + a1.x + a2.x + a3.x + self.x) * di);
    sp.y = softplus_f((a0.y + a1.y + a2.y + a3.y + self.y) * di);

    float ak = ((k0 + k1 + k2 + k3) + T2k[node]) * di;
    float kv = softplus_f(ak) + 0.1f;
    float g  = expf(lgammaf(1.0f + 1.0f / kv));
    if (lane == 0) kap_out[node] = kv;

    size_t o = (size_t)node * 128 + lane * 2;
    float2 zv = make_float2(sp.x * g, sp.y * g);
    *reinterpret_cast<float2*>(&lbd_out[o]) = sp;
    *reinterpret_cast<float2*>(&z_out[o])   = zv;
}

extern "C" void kernel_launch(void* const* d_in, const int* in_sizes, int n_in,
                              void* d_out, int out_size, void* d_ws, size_t ws_size,
                              hipStream_t stream)
{
    const float* x  = (const float*)d_in[0];
    const int*   ei = (const int*)d_in[1];
    const float* W0 = (const float*)d_in[2];
    const float* W1 = (const float*)d_in[3];

    const int N = in_sizes[0] / 512;      // 50000
    const int E = in_sizes[1] / 2;        // 1600000
    const int* src = ei;
    const int* dst = ei + E;

    const int mblocks = (N + 127) / 128;   // 391
    const int M_pad   = mblocks * 128;     // 50048
    const int nchunk  = (N + 1023) / 1024; // 49

    char* w = (char*)d_ws;
    size_t off = 0;
    auto take = [&](size_t bytes) -> void* {
        void* p = (void*)(w + off);
        off = (off + bytes + 255) & ~(size_t)255;
        return p;
    };
    int*      cnt    = (int*)take((size_t)N * 4);
    int*      rowptr = (int*)take((size_t)(N + 1) * 4);
    int*      cursor = (int*)take((size_t)N * 4);
    float*    dinv   = (float*)take((size_t)N * 4);
    int*      col    = (int*)take((size_t)E * 4);
    int*      blksum = (int*)take(64 * 4);
    int*      blkoff = (int*)take(64 * 4);
    ushort_t* W0bigT = (ushort_t*)take((size_t)256 * 1536 * 2);
    ushort_t* W1bigT = (ushort_t*)take((size_t)128 * 768 * 2);
    float*    W1col  = (float*)take((size_t)256 * 4);
    float*    T2k    = (float*)take((size_t)N * 4);
    float*    T1     = (float*)take((size_t)N * 256 * 4);   // T1s (prescaled)
    float*    T2     = T1;                 // T1s dead after agg1; reuse (T2s)
    ushort_t* Abig   = (ushort_t*)take((size_t)M_pad * 1024 * 2);   // 102.5 MB
    ushort_t* H1big  = Abig;               // alias: Abig dead after gemm1

    float* z_out   = (float*)d_out;
    float* lbd_out = z_out + (size_t)N * 128;
    float* kap_out = lbd_out + (size_t)N * 128;

    hipMemsetAsync(cnt, 0, (size_t)N * 4, stream);
    count_kernel<<<(E + 255) / 256, 256, 0, stream>>>(dst, cnt, E);
    scan_local<<<nchunk, 1024, 0, stream>>>(cnt, rowptr, dinv, blksum, N);
    scan_blk<<<1, 64, 0, stream>>>(blksum, blkoff, nchunk, rowptr, N);
    scan_add<<<(N + 255) / 256, 256, 0, stream>>>(rowptr, cursor, blkoff, N);
    scatter_kernel<<<(E + 255) / 256, 256, 0, stream>>>(src, dst, cursor, col, E);

    conv_x<<<(M_pad * 128) / 256, 256, 0, stream>>>(x, Abig, N, M_pad);
    conv_w0<<<(256 * 512) / 256, 256, 0, stream>>>(W0, W0bigT);
    conv_w1<<<(128 * 256) / 256, 256, 0, stream>>>(W1, W1bigT, W1col);

    // GEMM1: T1s = (x @ W0) * dinv[row]  (bf16x3 one pass, K=1536, A wraps at 1024)
    dim3 g1(mblocks, 2);
    gemm_bf16<<<g1, 256, 0, stream>>>(Abig, 1024, W0bigT, 1536, T1, 256, N, 1536, 1024, dinv);

    // agg1 split into two node-range halves (identical work; profiling window).
    const int half = ((N / 2) + 3) & ~3;   // 25000 (multiple of 4)
    agg1_kernel<<<(half + 3) / 4, 256, 0, stream>>>(T1, dinv, rowptr, col, W1col,
                                                    H1big, T2k, 0, half);
    agg1_kernel<<<(N - half + 3) / 4, 256, 0, stream>>>(T1, dinv, rowptr, col, W1col,
                                                        H1big, T2k, half, N);

    // GEMM2: T2s = (H1 @ W1main) * dinv[row]  (K=768, A wraps at 512)
    dim3 g2(mblocks, 1);
    gemm_bf16<<<g2, 256, 0, stream>>>(H1big, 512, W1bigT, 768, T2, 128, N, 768, 512, dinv);

    agg2_kernel<<<(N + 3) / 4, 256, 0, stream>>>(T2, T2k, dinv, rowptr, col,
                                                 z_out, lbd_out, kap_out, N);
}

// Round 9
// 730.504 us; speedup vs baseline: 1.1466x; 1.1466x over previous
//
#include <hip/hip_runtime.h>
#include <hip/hip_bf16.h>
#include <math.h>

// ---------------------------------------------------------------------------
// InfNet: 2-layer GCN + Weibull epilogue.
// GEMMs: bf16x3 split as ONE pass: [Ah|Al|Ah] * [Bh;Bh;Bl] via K-wrap remap,
// with dinv[row] scaling fused into the GEMM epilogue (T1s=(x@W0)*dinv,
// T2s=(H1@W1)*dinv; T2k prescaled by dinv).
// Aggregations fp32, wave-per-node (verified at the delivery-BW roofline:
// 1.69GB @ ~7.3TB/s across structural variants r1/r2/r4/r7).
// CSR build (r8 found it hidden at ~200us: 3.2M device atomics + 101MB of
// false-shared line flushes) replaced by a hierarchical LDS counting sort:
//   bucket_count: LDS hist over 98 buckets (dst>>9), 25K global atomics.
//   scan98: bucket starts (= col region bases; dst-major => contiguous).
//   partition: block-reserved ranges + LDS-cursor scatter of packed
//              (dstLocal<<16|src) into stage (4B/edge).
//   buildcsr: one block per bucket: LDS hist(512) -> local scan -> rowptr/
//             dinv coalesced -> LDS-cursor col scatter within a 65KB region
//             owned by ONE block/XCD (writes merge in its L2).
// ---------------------------------------------------------------------------

typedef unsigned short ushort_t;
typedef __attribute__((ext_vector_type(8))) short bf16x8;
typedef __attribute__((ext_vector_type(4))) float f32x4;

#define BSH 9            // 512 dst nodes per bucket
#define MAXB 128         // max buckets supported by scan98 (N<=65536)

__device__ __forceinline__ ushort_t f2bf(float f) {
    union { float f; unsigned u; } x; x.f = f;
    unsigned r = x.u + 0x7FFF + ((x.u >> 16) & 1);   // RNE
    return (ushort_t)(r >> 16);
}
__device__ __forceinline__ float bf2f(ushort_t s) {
    union { unsigned u; float f; } x; x.u = ((unsigned)s) << 16; return x.f;
}

__device__ __forceinline__ void async_copy16(const void* gsrc, void* ldst) {
    __builtin_amdgcn_global_load_lds(
        (const __attribute__((address_space(1))) unsigned int*)gsrc,
        (__attribute__((address_space(3))) unsigned int*)ldst,
        16, 0, 0);
}

// ---------------- graph preprocessing: hierarchical LDS counting sort ------

// per-block LDS histogram over coarse buckets; one global atomic per bucket.
__global__ __launch_bounds__(256) void bucket_count(const int* __restrict__ dst,
                                                    int* __restrict__ btot,
                                                    int E, int nbk)
{
    __shared__ int hist[MAXB];
    int tid = threadIdx.x;
    int per = (E + gridDim.x - 1) / gridDim.x;
    int lo  = blockIdx.x * per;
    int hi  = min(lo + per, E);
    for (int i = tid; i < nbk; i += 256) hist[i] = 0;
    __syncthreads();
    for (int i = lo + tid; i < hi; i += 256)
        atomicAdd(&hist[dst[i] >> BSH], 1);
    __syncthreads();
    for (int i = tid; i < nbk; i += 256)
        if (hist[i]) atomicAdd(&btot[i], hist[i]);
}

// exclusive scan of <=128 bucket totals; bstart[nbk] = E; bcursor = bstart.
__global__ __launch_bounds__(128) void scan98(const int* __restrict__ btot,
                                              int* __restrict__ bstart,
                                              int* __restrict__ bcursor, int nbk)
{
    __shared__ int ws[2];
    int tid = threadIdx.x, lane = tid & 63, wid = tid >> 6;
    int v = (tid < nbk) ? btot[tid] : 0;
    int s = v;
#pragma unroll
    for (int off = 1; off < 64; off <<= 1) {
        int t = __shfl_up(s, off, 64);
        if (lane >= off) s += t;
    }
    if (lane == 63) ws[wid] = s;
    __syncthreads();
    int excl = s - v + ((wid == 1) ? ws[0] : 0);
    if (tid < nbk) { bstart[tid] = excl; bcursor[tid] = excl; }
    if (tid == nbk - 1) bstart[nbk] = excl + v;   // = E
}

// scatter packed (dstLocal<<16 | src) into bucket-contiguous stage regions.
// per-(block,bucket) ranges reserved with ONE global atomic; positions via
// LDS cursor atomics -> block-contiguous writes.
__global__ __launch_bounds__(256) void partition_kernel(const int* __restrict__ src,
                                                        const int* __restrict__ dst,
                                                        int* __restrict__ bcursor,
                                                        int* __restrict__ stage,
                                                        int E, int nbk)
{
    __shared__ int hist[MAXB];
    int tid = threadIdx.x;
    int per = (E + gridDim.x - 1) / gridDim.x;
    int lo  = blockIdx.x * per;
    int hi  = min(lo + per, E);
    for (int i = tid; i < nbk; i += 256) hist[i] = 0;
    __syncthreads();
    for (int i = lo + tid; i < hi; i += 256)
        atomicAdd(&hist[dst[i] >> BSH], 1);
    __syncthreads();
    for (int i = tid; i < nbk; i += 256) {
        int c = hist[i];
        hist[i] = c ? atomicAdd(&bcursor[i], c) : 0;   // hist becomes cursor base
    }
    __syncthreads();
    for (int i = lo + tid; i < hi; i += 256) {
        int d = dst[i], s = src[i];
        int pos = atomicAdd(&hist[d >> BSH], 1);
        stage[pos] = ((d & ((1 << BSH) - 1)) << 16) | s;
    }
}

// one block per bucket: exact per-dst sort within the bucket's stage region.
// writes rowptr/dinv (coalesced) and col (scatter within 65KB, single XCD).
__global__ __launch_bounds__(256) void buildcsr(const int* __restrict__ stage,
                                                const int* __restrict__ bstart,
                                                int* __restrict__ rowptr,
                                                float* __restrict__ dinv,
                                                int* __restrict__ col,
                                                int N, int E)
{
    __shared__ int hist[512];
    __shared__ int excl[512];
    __shared__ int wsum[4];
    int g = blockIdx.x, tid = threadIdx.x;
    int ebeg = bstart[g], eend = bstart[g + 1];

    for (int i = tid; i < 512; i += 256) hist[i] = 0;
    __syncthreads();
    for (int i = ebeg + tid; i < eend; i += 256)
        atomicAdd(&hist[stage[i] >> 16], 1);
    __syncthreads();

    // exclusive scan over 512 bins (2 per thread)
    int h0 = hist[2 * tid], h1 = hist[2 * tid + 1];
    int ps = h0 + h1;
    int lane = tid & 63, wid = tid >> 6;
    int s = ps;
#pragma unroll
    for (int off = 1; off < 64; off <<= 1) {
        int t = __shfl_up(s, off, 64);
        if (lane >= off) s += t;
    }
    if (lane == 63) wsum[wid] = s;
    __syncthreads();
    if (tid < 4) {
        int w = wsum[tid];
#pragma unroll
        for (int off = 1; off < 4; off <<= 1) {
            int t = __shfl_up(w, off, 64);
            if (tid >= off) w += t;
        }
        wsum[tid] = w;
    }
    __syncthreads();
    int ex = s - ps + (wid ? wsum[wid - 1] : 0);
    excl[2 * tid]     = ex;
    excl[2 * tid + 1] = ex + h0;

    int nb0 = g << BSH;
#pragma unroll
    for (int q = 0; q < 2; ++q) {
        int binv = 2 * tid + q;
        int node = nb0 + binv;
        if (node < N) {
            rowptr[node] = ebeg + ((q == 0) ? ex : ex + h0);
            dinv[node]   = rsqrtf((float)(((q == 0) ? h0 : h1) + 1));
        }
    }
    if (g == gridDim.x - 1 && tid == 0) rowptr[N] = E;

    __syncthreads();
    for (int i = tid; i < 512; i += 256) hist[i] = ebeg + excl[i];  // -> cursors
    __syncthreads();
    for (int i = ebeg + tid; i < eend; i += 256) {
        int p = stage[i];
        int pos = atomicAdd(&hist[p >> 16], 1);
        col[pos] = p & 0xFFFF;
    }
}

// ---------------- operand conversion (bf16 hi/lo split) ----------------

__global__ __launch_bounds__(256) void conv_x(const float* __restrict__ x,
                                              ushort_t* __restrict__ Abig,
                                              int M, int M_pad)
{
    int id = blockIdx.x * blockDim.x + threadIdx.x;
    int r = id >> 7, q = id & 127;
    if (r >= M_pad) return;
    float4 v = make_float4(0.f, 0.f, 0.f, 0.f);
    if (r < M) v = *reinterpret_cast<const float4*>(&x[(size_t)r * 512 + q * 4]);
    ushort4 h, l;
    h.x = f2bf(v.x); l.x = f2bf(v.x - bf2f(h.x));
    h.y = f2bf(v.y); l.y = f2bf(v.y - bf2f(h.y));
    h.z = f2bf(v.z); l.z = f2bf(v.z - bf2f(h.z));
    h.w = f2bf(v.w); l.w = f2bf(v.w - bf2f(h.w));
    ushort_t* rowp = Abig + (size_t)r * 1024;
    *reinterpret_cast<ushort4*>(rowp + q * 4)       = h;
    *reinterpret_cast<ushort4*>(rowp + 512 + q * 4) = l;
}

// W0bigT (256 x 1536), row n: [hi(512) | hi(512) | lo(512)] of W0[:,n].
__global__ __launch_bounds__(256) void conv_w0(const float* __restrict__ W0,
                                               ushort_t* __restrict__ BT)
{
    int id = blockIdx.x * blockDim.x + threadIdx.x;
    int k = id & 511, n = id >> 9;
    if (n >= 256) return;
    float v = W0[(size_t)k * 256 + n];
    ushort_t h = f2bf(v);
    ushort_t l = f2bf(v - bf2f(h));
    ushort_t* rowp = BT + (size_t)n * 1536;
    rowp[k] = h; rowp[512 + k] = h; rowp[1024 + k] = l;
}

// W1bigT (128 x 768), row n: [hi(256) | hi(256) | lo(256)]; plus W1col fp32.
__global__ __launch_bounds__(256) void conv_w1(const float* __restrict__ W1,
                                               ushort_t* __restrict__ BT,
                                               float* __restrict__ W1col)
{
    int id = blockIdx.x * blockDim.x + threadIdx.x;
    int k = id & 255, n = id >> 8;
    if (n >= 128) return;
    float v = W1[(size_t)k * 129 + n];
    ushort_t h = f2bf(v);
    ushort_t l = f2bf(v - bf2f(h));
    ushort_t* rowp = BT + (size_t)n * 768;
    rowp[k] = h; rowp[256 + k] = h; rowp[512 + k] = l;
    if (n == 0) W1col[k] = W1[(size_t)k * 129 + 128];
}

// ---------------- MFMA GEMM: C = (A * BT^T) * rowscale[r] ----------------
// K iterates [0, K); A's k-index wraps at kwrap (so Ah reused for the Bl band).
// 128x128 tile, BK=32, 256 thr = 4 waves (2x2 of 64x64), 16x16x32 MFMA.
__global__ __launch_bounds__(256) void gemm_bf16(const ushort_t* __restrict__ A, int lda,
                                                 const ushort_t* __restrict__ BT, int ldbt,
                                                 float* __restrict__ C, int ldc,
                                                 int M, int K, int kwrap,
                                                 const float* __restrict__ rowscale)
{
    __shared__ short As[128 * 32];
    __shared__ short Bs[128 * 32];

    int tid  = threadIdx.x;
    int w    = tid >> 6;
    int lane = tid & 63;
    int lm   = lane & 15;
    int lq   = lane >> 4;
    int bm   = blockIdx.x * 128;
    int bn   = blockIdx.y * 128;
    int wr   = (w >> 1) * 64;
    int wc   = (w & 1) * 64;

    f32x4 acc[4][4];
#pragma unroll
    for (int i = 0; i < 4; ++i)
#pragma unroll
        for (int j = 0; j < 4; ++j) acc[i][j] = (f32x4)(0.f);

    int srow = (lane >> 2);
    int scol = (lane & 3) * 16;

    for (int k0 = 0; k0 < K; k0 += 32) {
        int ka = (k0 < kwrap) ? k0 : (k0 - kwrap);   // A k-wrap (tiles never straddle)
#pragma unroll
        for (int q = 0; q < 2; ++q) {
            int r = w * 32 + q * 16 + srow;
            const char* ga = (const char*)A + ((size_t)(bm + r) * lda + ka) * 2 + scol;
            async_copy16(ga, (char*)As + (size_t)(w * 32 + q * 16) * 64);
        }
#pragma unroll
        for (int q = 0; q < 2; ++q) {
            int r = w * 32 + q * 16 + srow;
            const char* gb = (const char*)BT + ((size_t)(bn + r) * ldbt + k0) * 2 + scol;
            async_copy16(gb, (char*)Bs + (size_t)(w * 32 + q * 16) * 64);
        }
        __syncthreads();

        bf16x8 afr[4], bfr[4];
#pragma unroll
        for (int mi = 0; mi < 4; ++mi)
            afr[mi] = *reinterpret_cast<const bf16x8*>(&As[(wr + mi * 16 + lm) * 32 + lq * 8]);
#pragma unroll
        for (int ni = 0; ni < 4; ++ni)
            bfr[ni] = *reinterpret_cast<const bf16x8*>(&Bs[(wc + ni * 16 + lm) * 32 + lq * 8]);
#pragma unroll
        for (int mi = 0; mi < 4; ++mi)
#pragma unroll
            for (int ni = 0; ni < 4; ++ni)
                acc[mi][ni] = __builtin_amdgcn_mfma_f32_16x16x32_bf16(
                    afr[mi], bfr[ni], acc[mi][ni], 0, 0, 0);
        __syncthreads();
    }

#pragma unroll
    for (int mi = 0; mi < 4; ++mi) {
        int rbase = bm + wr + mi * 16 + lq * 4;
        float rs[4];
#pragma unroll
        for (int e = 0; e < 4; ++e)                 // ni-invariant: hoisted
            rs[e] = (rbase + e < M) ? rowscale[rbase + e] : 0.f;
#pragma unroll
        for (int ni = 0; ni < 4; ++ni) {
            int cc = bn + wc + ni * 16 + lm;
#pragma unroll
            for (int e = 0; e < 4; ++e) {
                int r = rbase + e;
                if (r < M) C[(size_t)r * ldc + cc] = acc[mi][ni][e] * rs[e];
            }
        }
    }
}

// ---------------- fused pieces ----------------

__device__ __forceinline__ float softplus_f(float x)
{
    return fmaxf(x, 0.f) + log1pf(expf(-fabsf(x)));
}

__device__ __forceinline__ void add4(float4& a, const float4& v)
{
    a.x += v.x; a.y += v.y; a.z += v.z; a.w += v.w;
}

__device__ __forceinline__ void add2(float2& a, const float2& v)
{
    a.x += v.x; a.y += v.y;
}

// layer-1 aggregation + softplus -> H1big bf16 [hi(256) | lo(256)] per node;
// fused kappa column dot (T2ks = dinv * (H1 . W1col)).
// Wave-per-node; rows prescaled by dinv[src]; node range [node0, node1).
__global__ __launch_bounds__(256) void agg1_kernel(const float* __restrict__ T1s,
                                                   const float* __restrict__ dinv,
                                                   const int* __restrict__ rowptr,
                                                   const int* __restrict__ col,
                                                   const float* __restrict__ W1col,
                                                   ushort_t* __restrict__ H1big,
                                                   float* __restrict__ T2k,
                                                   int node0, int node1)
{
    int wslot = __builtin_amdgcn_readfirstlane(threadIdx.x >> 6);  // wave-uniform
    int node  = node0 + blockIdx.x * 4 + wslot;
    if (node >= node1) return;
    int lane = threadIdx.x & 63;
    float di = dinv[node];
    int beg = rowptr[node], end = rowptr[node + 1];

    float4 a0 = make_float4(0.f, 0.f, 0.f, 0.f);
    float4 a1 = a0, a2 = a0, a3 = a0;

    const float* Trow = T1s + (size_t)lane * 4;   // per-lane column offset

    int e = beg;
    for (; e + 4 <= end; e += 4) {
        int s0 = col[e], s1 = col[e + 1], s2 = col[e + 2], s3 = col[e + 3];
        float4 v0 = *reinterpret_cast<const float4*>(Trow + (size_t)s0 * 256);
        float4 v1 = *reinterpret_cast<const float4*>(Trow + (size_t)s1 * 256);
        float4 v2 = *reinterpret_cast<const float4*>(Trow + (size_t)s2 * 256);
        float4 v3 = *reinterpret_cast<const float4*>(Trow + (size_t)s3 * 256);
        add4(a0, v0); add4(a1, v1); add4(a2, v2); add4(a3, v3);
    }
    for (; e < end; ++e) {
        int s = col[e];
        float4 v = *reinterpret_cast<const float4*>(Trow + (size_t)s * 256);
        add4(a0, v);
    }

    float4 self = *reinterpret_cast<const float4*>(Trow + (size_t)node * 256);
    float4 o;
    o.x = softplus_f((a0.x + a1.x + a2.x + a3.x + self.x) * di);
    o.y = softplus_f((a0.y + a1.y + a2.y + a3.y + self.y) * di);
    o.z = softplus_f((a0.z + a1.z + a2.z + a3.z + self.z) * di);
    o.w = softplus_f((a0.w + a1.w + a2.w + a3.w + self.w) * di);

    ushort4 h, l;
    h.x = f2bf(o.x); l.x = f2bf(o.x - bf2f(h.x));
    h.y = f2bf(o.y); l.y = f2bf(o.y - bf2f(h.y));
    h.z = f2bf(o.z); l.z = f2bf(o.z - bf2f(h.z));
    h.w = f2bf(o.w); l.w = f2bf(o.w - bf2f(h.w));
    ushort_t* rowp = H1big + (size_t)node * 512;
    *reinterpret_cast<ushort4*>(rowp + lane * 4)       = h;
    *reinterpret_cast<ushort4*>(rowp + 256 + lane * 4) = l;

    // fused kappa column, prescaled: T2ks[node] = dinv[node] * (H1[node,:].W1col)
    float4 wv = *reinterpret_cast<const float4*>(&W1col[lane * 4]);
    float tk = o.x * wv.x + o.y * wv.y + o.z * wv.z + o.w * wv.w;
#pragma unroll
    for (int off = 32; off > 0; off >>= 1)
        tk += __shfl_down(tk, off, 64);
    if (lane == 0) T2k[node] = tk * di;
}

// layer-2 aggregation + softplus + Weibull epilogue. Wave-per-node; rows and
// T2k prescaled by dinv[src], so per edge: gather + add, T2k broadcast + add.
__global__ __launch_bounds__(256) void agg2_kernel(const float* __restrict__ T2s,
                                                   const float* __restrict__ T2k,
                                                   const float* __restrict__ dinv,
                                                   const int* __restrict__ rowptr,
                                                   const int* __restrict__ col,
                                                   float* __restrict__ z_out,
                                                   float* __restrict__ lbd_out,
                                                   float* __restrict__ kap_out, int N)
{
    int wslot = __builtin_amdgcn_readfirstlane(threadIdx.x >> 6);  // wave-uniform
    int node  = blockIdx.x * 4 + wslot;
    if (node >= N) return;
    int lane = threadIdx.x & 63;
    float di = dinv[node];
    int beg = rowptr[node], end = rowptr[node + 1];

    float2 a0 = make_float2(0.f, 0.f);
    float2 a1 = a0, a2 = a0, a3 = a0;
    float k0 = 0.f, k1 = 0.f, k2 = 0.f, k3 = 0.f;

    const float* Trow = T2s + (size_t)lane * 2;

    int e = beg;
    for (; e + 4 <= end; e += 4) {
        int s0 = col[e], s1 = col[e + 1], s2 = col[e + 2], s3 = col[e + 3];
        k0 += T2k[s0]; k1 += T2k[s1]; k2 += T2k[s2]; k3 += T2k[s3];
        float2 v0 = *reinterpret_cast<const float2*>(Trow + (size_t)s0 * 128);
        float2 v1 = *reinterpret_cast<const float2*>(Trow + (size_t)s1 * 128);
        float2 v2 = *reinterpret_cast<const float2*>(Trow + (size_t)s2 * 128);
        float2 v3 = *reinterpret_cast<const float2*>(Trow + (size_t)s3 * 128);
        add2(a0, v0); add2(a1, v1); add2(a2, v2); add2(a3, v3);
    }
    for (; e < end; ++e) {
        int s = col[e];
        k0 += T2k[s];
        float2 v = *reinterpret_cast<const float2*>(Trow + (size_t)s * 128);
        add2(a0, v);
    }

    float2 self = *reinterpret_cast<const float2*>(Trow + (size_t)node * 128);
    float2 sp;
    sp.x = softplus_f((a0.x + a1.x + a2.x + a3.x + self.x) * di);
    sp.y = softplus_f((a0.y + a1.y + a2.y + a3.y + self.y) * di);

    float ak = ((k0 + k1 + k2 + k3) + T2k[node]) * di;
    float kv = softplus_f(ak) + 0.1f;
    float g  = expf(lgammaf(1.0f + 1.0f / kv));
    if (lane == 0) kap_out[node] = kv;

    size_t o = (size_t)node * 128 + lane * 2;
    float2 zv = make_float2(sp.x * g, sp.y * g);
    *reinterpret_cast<float2*>(&lbd_out[o]) = sp;
    *reinterpret_cast<float2*>(&z_out[o])   = zv;
}

extern "C" void kernel_launch(void* const* d_in, const int* in_sizes, int n_in,
                              void* d_out, int out_size, void* d_ws, size_t ws_size,
                              hipStream_t stream)
{
    const float* x  = (const float*)d_in[0];
    const int*   ei = (const int*)d_in[1];
    const float* W0 = (const float*)d_in[2];
    const float* W1 = (const float*)d_in[3];

    const int N = in_sizes[0] / 512;      // 50000
    const int E = in_sizes[1] / 2;        // 1600000
    const int* src = ei;
    const int* dst = ei + E;

    const int mblocks = (N + 127) / 128;   // 391
    const int M_pad   = mblocks * 128;     // 50048
    const int nbk     = (N + 511) >> BSH;  // 98 coarse buckets

    char* w = (char*)d_ws;
    size_t off = 0;
    auto take = [&](size_t bytes) -> void* {
        void* p = (void*)(w + off);
        off = (off + bytes + 255) & ~(size_t)255;
        return p;
    };
    int*      rowptr = (int*)take((size_t)(N + 1) * 4);
    float*    dinv   = (float*)take((size_t)N * 4);
    int*      col    = (int*)take((size_t)E * 4);
    int*      stage  = (int*)take((size_t)E * 4);
    int*      btot   = (int*)take((size_t)MAXB * 4);
    int*      bstart = (int*)take((size_t)(MAXB + 1) * 4);
    int*      bcursor= (int*)take((size_t)MAXB * 4);
    ushort_t* W0bigT = (ushort_t*)take((size_t)256 * 1536 * 2);
    ushort_t* W1bigT = (ushort_t*)take((size_t)128 * 768 * 2);
    float*    W1col  = (float*)take((size_t)256 * 4);
    float*    T2k    = (float*)take((size_t)N * 4);
    float*    T1     = (float*)take((size_t)N * 256 * 4);   // T1s (prescaled)
    float*    T2     = T1;                 // T1s dead after agg1; reuse (T2s)
    ushort_t* Abig   = (ushort_t*)take((size_t)M_pad * 1024 * 2);   // 102.5 MB
    ushort_t* H1big  = Abig;               // alias: Abig dead after gemm1

    float* z_out   = (float*)d_out;
    float* lbd_out = z_out + (size_t)N * 128;
    float* kap_out = lbd_out + (size_t)N * 128;

    // ---- CSR build: hierarchical LDS counting sort ----
    hipMemsetAsync(btot, 0, (size_t)MAXB * 4, stream);
    bucket_count<<<256, 256, 0, stream>>>(dst, btot, E, nbk);
    scan98<<<1, 128, 0, stream>>>(btot, bstart, bcursor, nbk);
    partition_kernel<<<256, 256, 0, stream>>>(src, dst, bcursor, stage, E, nbk);
    buildcsr<<<nbk, 256, 0, stream>>>(stage, bstart, rowptr, dinv, col, N, E);

    conv_x<<<(M_pad * 128) / 256, 256, 0, stream>>>(x, Abig, N, M_pad);
    conv_w0<<<(256 * 512) / 256, 256, 0, stream>>>(W0, W0bigT);
    conv_w1<<<(128 * 256) / 256, 256, 0, stream>>>(W1, W1bigT, W1col);

    // GEMM1: T1s = (x @ W0) * dinv[row]  (bf16x3 one pass, K=1536, A wraps at 1024)
    dim3 g1(mblocks, 2);
    gemm_bf16<<<g1, 256, 0, stream>>>(Abig, 1024, W0bigT, 1536, T1, 256, N, 1536, 1024, dinv);

    // agg1 split into two node-range halves (identical work; profiling window).
    const int half = ((N / 2) + 3) & ~3;   // 25000 (multiple of 4)
    agg1_kernel<<<(half + 3) / 4, 256, 0, stream>>>(T1, dinv, rowptr, col, W1col,
                                                    H1big, T2k, 0, half);
    agg1_kernel<<<(N - half + 3) / 4, 256, 0, stream>>>(T1, dinv, rowptr, col, W1col,
                                                        H1big, T2k, half, N);

    // GEMM2: T2s = (H1 @ W1main) * dinv[row]  (K=768, A wraps at 512)
    dim3 g2(mblocks, 1);
    gemm_bf16<<<g2, 256, 0, stream>>>(H1big, 512, W1bigT, 768, T2, 128, N, 768, 512, dinv);

    agg2_kernel<<<(N + 3) / 4, 256, 0, stream>>>(T2, T2k, dinv, rowptr, col,
                                                 z_out, lbd_out, kap_out, N);
}

// Round 10
// 703.085 us; speedup vs baseline: 1.1913x; 1.0390x over previous
//
#include <hip/hip_runtime.h>
#include <hip/hip_bf16.h>
#include <math.h>

// ---------------------------------------------------------------------------
// InfNet: 2-layer GCN + Weibull epilogue.
// GEMM1 is FUSED with the x->bf16 hi/lo conversion: 128x256 tile (8 waves),
// K-loop over x-chunks; per chunk the three bf16x3 band products
// AhBh + AlBh + AhBl are computed from one staged x tile. x is read ONCE
// (102 MB) vs conv_x+Abig's 512 MB. dinv row-scaling fused in the epilogue.
// GEMM2 keeps the K-wrap bf16x3 kernel (A = H1 bf16 hi/lo, written by agg1).
// Aggregations fp32, wave-per-node — at the fabric-BW roofline (840MB @
// 3.5TB/s, r7/r9); both aggs split into 2 node-range dispatches for
// profiler visibility (r8 trick that exposed the hidden scatter cost).
// CSR build: hierarchical LDS counting sort (r9: saved ~107us vs atomics).
// ---------------------------------------------------------------------------

typedef unsigned short ushort_t;
typedef __attribute__((ext_vector_type(8))) short bf16x8;
typedef __attribute__((ext_vector_type(4))) float f32x4;

#define BSH 9            // 512 dst nodes per bucket
#define MAXB 128         // max buckets supported by scan98 (N<=65536)

__device__ __forceinline__ ushort_t f2bf(float f) {
    union { float f; unsigned u; } x; x.f = f;
    unsigned r = x.u + 0x7FFF + ((x.u >> 16) & 1);   // RNE
    return (ushort_t)(r >> 16);
}
__device__ __forceinline__ float bf2f(ushort_t s) {
    union { unsigned u; float f; } x; x.u = ((unsigned)s) << 16; return x.f;
}

__device__ __forceinline__ void async_copy16(const void* gsrc, void* ldst) {
    __builtin_amdgcn_global_load_lds(
        (const __attribute__((address_space(1))) unsigned int*)gsrc,
        (__attribute__((address_space(3))) unsigned int*)ldst,
        16, 0, 0);
}

// ---------------- graph preprocessing: hierarchical LDS counting sort ------

__global__ __launch_bounds__(256) void bucket_count(const int* __restrict__ dst,
                                                    int* __restrict__ btot,
                                                    int E, int nbk)
{
    __shared__ int hist[MAXB];
    int tid = threadIdx.x;
    int per = (E + gridDim.x - 1) / gridDim.x;
    int lo  = blockIdx.x * per;
    int hi  = min(lo + per, E);
    for (int i = tid; i < nbk; i += 256) hist[i] = 0;
    __syncthreads();
    for (int i = lo + tid; i < hi; i += 256)
        atomicAdd(&hist[dst[i] >> BSH], 1);
    __syncthreads();
    for (int i = tid; i < nbk; i += 256)
        if (hist[i]) atomicAdd(&btot[i], hist[i]);
}

__global__ __launch_bounds__(128) void scan98(const int* __restrict__ btot,
                                              int* __restrict__ bstart,
                                              int* __restrict__ bcursor, int nbk)
{
    __shared__ int ws[2];
    int tid = threadIdx.x, lane = tid & 63, wid = tid >> 6;
    int v = (tid < nbk) ? btot[tid] : 0;
    int s = v;
#pragma unroll
    for (int off = 1; off < 64; off <<= 1) {
        int t = __shfl_up(s, off, 64);
        if (lane >= off) s += t;
    }
    if (lane == 63) ws[wid] = s;
    __syncthreads();
    int excl = s - v + ((wid == 1) ? ws[0] : 0);
    if (tid < nbk) { bstart[tid] = excl; bcursor[tid] = excl; }
    if (tid == nbk - 1) bstart[nbk] = excl + v;   // = E
}

__global__ __launch_bounds__(256) void partition_kernel(const int* __restrict__ src,
                                                        const int* __restrict__ dst,
                                                        int* __restrict__ bcursor,
                                                        int* __restrict__ stage,
                                                        int E, int nbk)
{
    __shared__ int hist[MAXB];
    int tid = threadIdx.x;
    int per = (E + gridDim.x - 1) / gridDim.x;
    int lo  = blockIdx.x * per;
    int hi  = min(lo + per, E);
    for (int i = tid; i < nbk; i += 256) hist[i] = 0;
    __syncthreads();
    for (int i = lo + tid; i < hi; i += 256)
        atomicAdd(&hist[dst[i] >> BSH], 1);
    __syncthreads();
    for (int i = tid; i < nbk; i += 256) {
        int c = hist[i];
        hist[i] = c ? atomicAdd(&bcursor[i], c) : 0;   // hist becomes cursor base
    }
    __syncthreads();
    for (int i = lo + tid; i < hi; i += 256) {
        int d = dst[i], s = src[i];
        int pos = atomicAdd(&hist[d >> BSH], 1);
        stage[pos] = ((d & ((1 << BSH) - 1)) << 16) | s;
    }
}

__global__ __launch_bounds__(256) void buildcsr(const int* __restrict__ stage,
                                                const int* __restrict__ bstart,
                                                int* __restrict__ rowptr,
                                                float* __restrict__ dinv,
                                                int* __restrict__ col,
                                                int N, int E)
{
    __shared__ int hist[512];
    __shared__ int excl[512];
    __shared__ int wsum[4];
    int g = blockIdx.x, tid = threadIdx.x;
    int ebeg = bstart[g], eend = bstart[g + 1];

    for (int i = tid; i < 512; i += 256) hist[i] = 0;
    __syncthreads();
    for (int i = ebeg + tid; i < eend; i += 256)
        atomicAdd(&hist[stage[i] >> 16], 1);
    __syncthreads();

    int h0 = hist[2 * tid], h1 = hist[2 * tid + 1];
    int ps = h0 + h1;
    int lane = tid & 63, wid = tid >> 6;
    int s = ps;
#pragma unroll
    for (int off = 1; off < 64; off <<= 1) {
        int t = __shfl_up(s, off, 64);
        if (lane >= off) s += t;
    }
    if (lane == 63) wsum[wid] = s;
    __syncthreads();
    if (tid < 4) {
        int w = wsum[tid];
#pragma unroll
        for (int off = 1; off < 4; off <<= 1) {
            int t = __shfl_up(w, off, 64);
            if (tid >= off) w += t;
        }
        wsum[tid] = w;
    }
    __syncthreads();
    int ex = s - ps + (wid ? wsum[wid - 1] : 0);
    excl[2 * tid]     = ex;
    excl[2 * tid + 1] = ex + h0;

    int nb0 = g << BSH;
#pragma unroll
    for (int q = 0; q < 2; ++q) {
        int binv = 2 * tid + q;
        int node = nb0 + binv;
        if (node < N) {
            rowptr[node] = ebeg + ((q == 0) ? ex : ex + h0);
            dinv[node]   = rsqrtf((float)(((q == 0) ? h0 : h1) + 1));
        }
    }
    if (g == gridDim.x - 1 && tid == 0) rowptr[N] = E;

    __syncthreads();
    for (int i = tid; i < 512; i += 256) hist[i] = ebeg + excl[i];  // -> cursors
    __syncthreads();
    for (int i = ebeg + tid; i < eend; i += 256) {
        int p = stage[i];
        int pos = atomicAdd(&hist[p >> 16], 1);
        col[pos] = p & 0xFFFF;
    }
}

// ---------------- weight conversion (bf16 hi/lo split) ----------------

// W0bigT (256 x 1536), row n: [hi(512) | hi(512) | lo(512)] of W0[:,n].
__global__ __launch_bounds__(256) void conv_w0(const float* __restrict__ W0,
                                               ushort_t* __restrict__ BT)
{
    int id = blockIdx.x * blockDim.x + threadIdx.x;
    int k = id & 511, n = id >> 9;
    if (n >= 256) return;
    float v = W0[(size_t)k * 256 + n];
    ushort_t h = f2bf(v);
    ushort_t l = f2bf(v - bf2f(h));
    ushort_t* rowp = BT + (size_t)n * 1536;
    rowp[k] = h; rowp[512 + k] = h; rowp[1024 + k] = l;
}

// W1bigT (128 x 768), row n: [hi(256) | hi(256) | lo(256)]; plus W1col fp32.
__global__ __launch_bounds__(256) void conv_w1(const float* __restrict__ W1,
                                               ushort_t* __restrict__ BT,
                                               float* __restrict__ W1col)
{
    int id = blockIdx.x * blockDim.x + threadIdx.x;
    int k = id & 255, n = id >> 8;
    if (n >= 128) return;
    float v = W1[(size_t)k * 129 + n];
    ushort_t h = f2bf(v);
    ushort_t l = f2bf(v - bf2f(h));
    ushort_t* rowp = BT + (size_t)n * 768;
    rowp[k] = h; rowp[256 + k] = h; rowp[512 + k] = l;
    if (n == 0) W1col[k] = W1[(size_t)k * 129 + 128];
}

// ---------------- GEMM1 fused: T1s = (x @ W0) * dinv, conversion in-kernel --
// 128x256 tile, 512 thr = 8 waves (2x4 of 64x64). Per x-chunk kc (16 iters):
// stage Ah/Al (reg-convert) + Bh/Bl (async), then 3 band products
// AhBh + AlBh + AhBl (48 MFMA/wave). Same hi/lo rounding as the old conv_x;
// only fp32 MFMA accumulation order differs (reassociation noise).
__global__ __launch_bounds__(512) void gemm1_fused(const float* __restrict__ x,
                                                   const ushort_t* __restrict__ BT,
                                                   float* __restrict__ C,
                                                   int M,
                                                   const float* __restrict__ rowscale)
{
    __shared__ short Ah[128 * 32];
    __shared__ short Al[128 * 32];
    __shared__ short Bh[256 * 32];
    __shared__ short Bl[256 * 32];

    int tid  = threadIdx.x;
    int w    = tid >> 6;        // 0..7
    int lane = tid & 63;
    int lm   = lane & 15;
    int lq   = lane >> 4;
    int bm   = blockIdx.x * 128;
    int wr   = (w >> 2) * 64;   // 0 or 64
    int wc   = (w & 3) * 64;    // 0,64,128,192

    f32x4 acc[4][4];
#pragma unroll
    for (int i = 0; i < 4; ++i)
#pragma unroll
        for (int j = 0; j < 4; ++j) acc[i][j] = (f32x4)(0.f);

    int arow = tid >> 3;        // 0..63
    int acol = (tid & 7) * 4;   // 0,4,...,28

    for (int kc = 0; kc < 512; kc += 32) {
        // A: direct from x, hi/lo split in-register (predicated tail rows)
#pragma unroll
        for (int p = 0; p < 2; ++p) {
            int r  = arow + p * 64;
            int rg = bm + r;
            float4 v = make_float4(0.f, 0.f, 0.f, 0.f);
            if (rg < M) v = *reinterpret_cast<const float4*>(&x[(size_t)rg * 512 + kc + acol]);
            ushort4 h, l;
            h.x = f2bf(v.x); l.x = f2bf(v.x - bf2f(h.x));
            h.y = f2bf(v.y); l.y = f2bf(v.y - bf2f(h.y));
            h.z = f2bf(v.z); l.z = f2bf(v.z - bf2f(h.z));
            h.w = f2bf(v.w); l.w = f2bf(v.w - bf2f(h.w));
            *reinterpret_cast<ushort4*>(&Ah[r * 32 + acol]) = h;
            *reinterpret_cast<ushort4*>(&Al[r * 32 + acol]) = l;
        }
        // B: async global->LDS; Bh band at col 0, Bl band at col 1024.
#pragma unroll
        for (int p = 0; p < 2; ++p) {
            int row = w * 16 + p * 128 + (lane >> 2);
            int seg = lane & 3;
            const char* gh = (const char*)BT + ((size_t)row * 1536 + kc) * 2 + seg * 16;
            async_copy16(gh, (char*)Bh + (size_t)row * 64 + seg * 16);
            const char* gl = (const char*)BT + ((size_t)row * 1536 + 1024 + kc) * 2 + seg * 16;
            async_copy16(gl, (char*)Bl + (size_t)row * 64 + seg * 16);
        }
        __syncthreads();

        bf16x8 ah[4], al[4];
#pragma unroll
        for (int mi = 0; mi < 4; ++mi) {
            ah[mi] = *reinterpret_cast<const bf16x8*>(&Ah[(wr + mi * 16 + lm) * 32 + lq * 8]);
            al[mi] = *reinterpret_cast<const bf16x8*>(&Al[(wr + mi * 16 + lm) * 32 + lq * 8]);
        }
#pragma unroll
        for (int ni = 0; ni < 4; ++ni) {
            bf16x8 bh = *reinterpret_cast<const bf16x8*>(&Bh[(wc + ni * 16 + lm) * 32 + lq * 8]);
            bf16x8 bl = *reinterpret_cast<const bf16x8*>(&Bl[(wc + ni * 16 + lm) * 32 + lq * 8]);
#pragma unroll
            for (int mi = 0; mi < 4; ++mi)
                acc[mi][ni] = __builtin_amdgcn_mfma_f32_16x16x32_bf16(ah[mi], bh, acc[mi][ni], 0, 0, 0);
#pragma unroll
            for (int mi = 0; mi < 4; ++mi)
                acc[mi][ni] = __builtin_amdgcn_mfma_f32_16x16x32_bf16(al[mi], bh, acc[mi][ni], 0, 0, 0);
#pragma unroll
            for (int mi = 0; mi < 4; ++mi)
                acc[mi][ni] = __builtin_amdgcn_mfma_f32_16x16x32_bf16(ah[mi], bl, acc[mi][ni], 0, 0, 0);
        }
        __syncthreads();
    }

#pragma unroll
    for (int mi = 0; mi < 4; ++mi) {
        int rbase = bm + wr + mi * 16 + lq * 4;
        float rs[4];
#pragma unroll
        for (int e = 0; e < 4; ++e)
            rs[e] = (rbase + e < M) ? rowscale[rbase + e] : 0.f;
#pragma unroll
        for (int ni = 0; ni < 4; ++ni) {
            int cc = wc + ni * 16 + lm;
#pragma unroll
            for (int e = 0; e < 4; ++e) {
                int r = rbase + e;
                if (r < M) C[(size_t)r * 256 + cc] = acc[mi][ni][e] * rs[e];
            }
        }
    }
}

// ---------------- GEMM2 (K-wrap bf16x3): C = (A * BT^T) * rowscale ---------
// 128x128 tile, BK=32, 256 thr = 4 waves (2x2 of 64x64), 16x16x32 MFMA.
__global__ __launch_bounds__(256) void gemm_bf16(const ushort_t* __restrict__ A, int lda,
                                                 const ushort_t* __restrict__ BT, int ldbt,
                                                 float* __restrict__ C, int ldc,
                                                 int M, int K, int kwrap,
                                                 const float* __restrict__ rowscale)
{
    __shared__ short As[128 * 32];
    __shared__ short Bs[128 * 32];

    int tid  = threadIdx.x;
    int w    = tid >> 6;
    int lane = tid & 63;
    int lm   = lane & 15;
    int lq   = lane >> 4;
    int bm   = blockIdx.x * 128;
    int bn   = blockIdx.y * 128;
    int wr   = (w >> 1) * 64;
    int wc   = (w & 1) * 64;

    f32x4 acc[4][4];
#pragma unroll
    for (int i = 0; i < 4; ++i)
#pragma unroll
        for (int j = 0; j < 4; ++j) acc[i][j] = (f32x4)(0.f);

    int srow = (lane >> 2);
    int scol = (lane & 3) * 16;

    for (int k0 = 0; k0 < K; k0 += 32) {
        int ka = (k0 < kwrap) ? k0 : (k0 - kwrap);   // A k-wrap (tiles never straddle)
#pragma unroll
        for (int q = 0; q < 2; ++q) {
            int r = w * 32 + q * 16 + srow;
            const char* ga = (const char*)A + ((size_t)(bm + r) * lda + ka) * 2 + scol;
            async_copy16(ga, (char*)As + (size_t)(w * 32 + q * 16) * 64);
        }
#pragma unroll
        for (int q = 0; q < 2; ++q) {
            int r = w * 32 + q * 16 + srow;
            const char* gb = (const char*)BT + ((size_t)(bn + r) * ldbt + k0) * 2 + scol;
            async_copy16(gb, (char*)Bs + (size_t)(w * 32 + q * 16) * 64);
        }
        __syncthreads();

        bf16x8 afr[4], bfr[4];
#pragma unroll
        for (int mi = 0; mi < 4; ++mi)
            afr[mi] = *reinterpret_cast<const bf16x8*>(&As[(wr + mi * 16 + lm) * 32 + lq * 8]);
#pragma unroll
        for (int ni = 0; ni < 4; ++ni)
            bfr[ni] = *reinterpret_cast<const bf16x8*>(&Bs[(wc + ni * 16 + lm) * 32 + lq * 8]);
#pragma unroll
        for (int mi = 0; mi < 4; ++mi)
#pragma unroll
            for (int ni = 0; ni < 4; ++ni)
                acc[mi][ni] = __builtin_amdgcn_mfma_f32_16x16x32_bf16(
                    afr[mi], bfr[ni], acc[mi][ni], 0, 0, 0);
        __syncthreads();
    }

#pragma unroll
    for (int mi = 0; mi < 4; ++mi) {
        int rbase = bm + wr + mi * 16 + lq * 4;
        float rs[4];
#pragma unroll
        for (int e = 0; e < 4; ++e)
            rs[e] = (rbase + e < M) ? rowscale[rbase + e] : 0.f;
#pragma unroll
        for (int ni = 0; ni < 4; ++ni) {
            int cc = bn + wc + ni * 16 + lm;
#pragma unroll
            for (int e = 0; e < 4; ++e) {
                int r = rbase + e;
                if (r < M) C[(size_t)r * ldc + cc] = acc[mi][ni][e] * rs[e];
            }
        }
    }
}

// ---------------- fused pieces ----------------

__device__ __forceinline__ float softplus_f(float x)
{
    return fmaxf(x, 0.f) + log1pf(expf(-fabsf(x)));
}

__device__ __forceinline__ void add4(float4& a, const float4& v)
{
    a.x += v.x; a.y += v.y; a.z += v.z; a.w += v.w;
}

__device__ __forceinline__ void add2(float2& a, const float2& v)
{
    a.x += v.x; a.y += v.y;
}

// layer-1 aggregation + softplus -> H1big bf16 [hi(256) | lo(256)] per node;
// fused kappa column dot (T2ks = dinv * (H1 . W1col)). Wave-per-node.
__global__ __launch_bounds__(256) void agg1_kernel(const float* __restrict__ T1s,
                                                   const float* __restrict__ dinv,
                                                   const int* __restrict__ rowptr,
                                                   const int* __restrict__ col,
                                                   const float* __restrict__ W1col,
                                                   ushort_t* __restrict__ H1big,
                                                   float* __restrict__ T2k,
                                                   int node0, int node1)
{
    int wslot = __builtin_amdgcn_readfirstlane(threadIdx.x >> 6);  // wave-uniform
    int node  = node0 + blockIdx.x * 4 + wslot;
    if (node >= node1) return;
    int lane = threadIdx.x & 63;
    float di = dinv[node];
    int beg = rowptr[node], end = rowptr[node + 1];

    float4 a0 = make_float4(0.f, 0.f, 0.f, 0.f);
    float4 a1 = a0, a2 = a0, a3 = a0;

    const float* Trow = T1s + (size_t)lane * 4;   // per-lane column offset

    int e = beg;
    for (; e + 4 <= end; e += 4) {
        int s0 = col[e], s1 = col[e + 1], s2 = col[e + 2], s3 = col[e + 3];
        float4 v0 = *reinterpret_cast<const float4*>(Trow + (size_t)s0 * 256);
        float4 v1 = *reinterpret_cast<const float4*>(Trow + (size_t)s1 * 256);
        float4 v2 = *reinterpret_cast<const float4*>(Trow + (size_t)s2 * 256);
        float4 v3 = *reinterpret_cast<const float4*>(Trow + (size_t)s3 * 256);
        add4(a0, v0); add4(a1, v1); add4(a2, v2); add4(a3, v3);
    }
    for (; e < end; ++e) {
        int s = col[e];
        float4 v = *reinterpret_cast<const float4*>(Trow + (size_t)s * 256);
        add4(a0, v);
    }

    float4 self = *reinterpret_cast<const float4*>(Trow + (size_t)node * 256);
    float4 o;
    o.x = softplus_f((a0.x + a1.x + a2.x + a3.x + self.x) * di);
    o.y = softplus_f((a0.y + a1.y + a2.y + a3.y + self.y) * di);
    o.z = softplus_f((a0.z + a1.z + a2.z + a3.z + self.z) * di);
    o.w = softplus_f((a0.w + a1.w + a2.w + a3.w + self.w) * di);

    ushort4 h, l;
    h.x = f2bf(o.x); l.x = f2bf(o.x - bf2f(h.x));
    h.y = f2bf(o.y); l.y = f2bf(o.y - bf2f(h.y));
    h.z = f2bf(o.z); l.z = f2bf(o.z - bf2f(h.z));
    h.w = f2bf(o.w); l.w = f2bf(o.w - bf2f(h.w));
    ushort_t* rowp = H1big + (size_t)node * 512;
    *reinterpret_cast<ushort4*>(rowp + lane * 4)       = h;
    *reinterpret_cast<ushort4*>(rowp + 256 + lane * 4) = l;

    // fused kappa column, prescaled: T2ks[node] = dinv[node] * (H1[node,:].W1col)
    float4 wv = *reinterpret_cast<const float4*>(&W1col[lane * 4]);
    float tk = o.x * wv.x + o.y * wv.y + o.z * wv.z + o.w * wv.w;
#pragma unroll
    for (int off = 32; off > 0; off >>= 1)
        tk += __shfl_down(tk, off, 64);
    if (lane == 0) T2k[node] = tk * di;
}

// layer-2 aggregation + softplus + Weibull epilogue. Wave-per-node.
__global__ __launch_bounds__(256) void agg2_kernel(const float* __restrict__ T2s,
                                                   const float* __restrict__ T2k,
                                                   const float* __restrict__ dinv,
                                                   const int* __restrict__ rowptr,
                                                   const int* __restrict__ col,
                                                   float* __restrict__ z_out,
                                                   float* __restrict__ lbd_out,
                                                   float* __restrict__ kap_out,
                                                   int node0, int node1)
{
    int wslot = __builtin_amdgcn_readfirstlane(threadIdx.x >> 6);  // wave-uniform
    int node  = node0 + blockIdx.x * 4 + wslot;
    if (node >= node1) return;
    int lane = threadIdx.x & 63;
    float di = dinv[node];
    int beg = rowptr[node], end = rowptr[node + 1];

    float2 a0 = make_float2(0.f, 0.f);
    float2 a1 = a0, a2 = a0, a3 = a0;
    float k0 = 0.f, k1 = 0.f, k2 = 0.f, k3 = 0.f;

    const float* Trow = T2s + (size_t)lane * 2;

    int e = beg;
    for (; e + 4 <= end; e += 4) {
        int s0 = col[e], s1 = col[e + 1], s2 = col[e + 2], s3 = col[e + 3];
        k0 += T2k[s0]; k1 += T2k[s1]; k2 += T2k[s2]; k3 += T2k[s3];
        float2 v0 = *reinterpret_cast<const float2*>(Trow + (size_t)s0 * 128);
        float2 v1 = *reinterpret_cast<const float2*>(Trow + (size_t)s1 * 128);
        float2 v2 = *reinterpret_cast<const float2*>(Trow + (size_t)s2 * 128);
        float2 v3 = *reinterpret_cast<const float2*>(Trow + (size_t)s3 * 128);
        add2(a0, v0); add2(a1, v1); add2(a2, v2); add2(a3, v3);
    }
    for (; e < end; ++e) {
        int s = col[e];
        k0 += T2k[s];
        float2 v = *reinterpret_cast<const float2*>(Trow + (size_t)s * 128);
        add2(a0, v);
    }

    float2 self = *reinterpret_cast<const float2*>(Trow + (size_t)node * 128);
    float2 sp;
    sp.x = softplus_f((a0.x + a1.x + a2.x + a3.x + self.x) * di);
    sp.y = softplus_f((a0.y + a1.y + a2.y + a3.y + self.y) * di);

    float ak = ((k0 + k1 + k2 + k3) + T2k[node]) * di;
    float kv = softplus_f(ak) + 0.1f;
    float g  = expf(lgammaf(1.0f + 1.0f / kv));
    if (lane == 0) kap_out[node] = kv;

    size_t o = (size_t)node * 128 + lane * 2;
    float2 zv = make_float2(sp.x * g, sp.y * g);
    *reinterpret_cast<float2*>(&lbd_out[o]) = sp;
    *reinterpret_cast<float2*>(&z_out[o])   = zv;
}

extern "C" void kernel_launch(void* const* d_in, const int* in_sizes, int n_in,
                              void* d_out, int out_size, void* d_ws, size_t ws_size,
                              hipStream_t stream)
{
    const float* x  = (const float*)d_in[0];
    const int*   ei = (const int*)d_in[1];
    const float* W0 = (const float*)d_in[2];
    const float* W1 = (const float*)d_in[3];

    const int N = in_sizes[0] / 512;      // 50000
    const int E = in_sizes[1] / 2;        // 1600000
    const int* src = ei;
    const int* dst = ei + E;

    const int mblocks = (N + 127) / 128;   // 391
    const int M_pad   = mblocks * 128;     // 50048
    const int nbk     = (N + 511) >> BSH;  // 98 coarse buckets

    char* w = (char*)d_ws;
    size_t off = 0;
    auto take = [&](size_t bytes) -> void* {
        void* p = (void*)(w + off);
        off = (off + bytes + 255) & ~(size_t)255;
        return p;
    };
    int*      rowptr = (int*)take((size_t)(N + 1) * 4);
    float*    dinv   = (float*)take((size_t)N * 4);
    int*      col    = (int*)take((size_t)E * 4);
    int*      stage  = (int*)take((size_t)E * 4);
    int*      btot   = (int*)take((size_t)MAXB * 4);
    int*      bstart = (int*)take((size_t)(MAXB + 1) * 4);
    int*      bcursor= (int*)take((size_t)MAXB * 4);
    ushort_t* W0bigT = (ushort_t*)take((size_t)256 * 1536 * 2);
    ushort_t* W1bigT = (ushort_t*)take((size_t)128 * 768 * 2);
    float*    W1col  = (float*)take((size_t)256 * 4);
    float*    T2k    = (float*)take((size_t)N * 4);
    float*    T1     = (float*)take((size_t)N * 256 * 4);   // T1s (prescaled)
    float*    T2     = T1;                 // T1s dead after agg1; reuse (T2s)
    ushort_t* H1big  = (ushort_t*)take((size_t)M_pad * 512 * 2);   // 51.2 MB

    float* z_out   = (float*)d_out;
    float* lbd_out = z_out + (size_t)N * 128;
    float* kap_out = lbd_out + (size_t)N * 128;

    // ---- CSR build: hierarchical LDS counting sort ----
    hipMemsetAsync(btot, 0, (size_t)MAXB * 4, stream);
    bucket_count<<<256, 256, 0, stream>>>(dst, btot, E, nbk);
    scan98<<<1, 128, 0, stream>>>(btot, bstart, bcursor, nbk);
    partition_kernel<<<256, 256, 0, stream>>>(src, dst, bcursor, stage, E, nbk);
    buildcsr<<<nbk, 256, 0, stream>>>(stage, bstart, rowptr, dinv, col, N, E);

    conv_w0<<<(256 * 512) / 256, 256, 0, stream>>>(W0, W0bigT);
    conv_w1<<<(128 * 256) / 256, 256, 0, stream>>>(W1, W1bigT, W1col);

    // GEMM1 fused: T1s = (x @ W0) * dinv[row], x read once, conversion in-kernel.
    gemm1_fused<<<mblocks, 512, 0, stream>>>(x, W0bigT, T1, N, dinv);

    // agg1 split into two node-range halves (identical work; profiling window).
    const int half = ((N / 2) + 3) & ~3;   // 25000 (multiple of 4)
    agg1_kernel<<<(half + 3) / 4, 256, 0, stream>>>(T1, dinv, rowptr, col, W1col,
                                                    H1big, T2k, 0, half);
    agg1_kernel<<<(N - half + 3) / 4, 256, 0, stream>>>(T1, dinv, rowptr, col, W1col,
                                                        H1big, T2k, half, N);

    // GEMM2: T2s = (H1 @ W1main) * dinv[row]  (K=768, A wraps at 512)
    dim3 g2(mblocks, 1);
    gemm_bf16<<<g2, 256, 0, stream>>>(H1big, 512, W1bigT, 768, T2, 128, N, 768, 512, dinv);

    // agg2 split likewise.
    agg2_kernel<<<(half + 3) / 4, 256, 0, stream>>>(T2, T2k, dinv, rowptr, col,
                                                    z_out, lbd_out, kap_out, 0, half);
    agg2_kernel<<<(N - half + 3) / 4, 256, 0, stream>>>(T2, T2k, dinv, rowptr, col,
                                                        z_out, lbd_out, kap_out, half, N);
}